// Round 1
// baseline (469.787 us; speedup 1.0000x reference)
//
#include <hip/hip_runtime.h>

// ---------------- problem constants ----------------
#define B_SZ   256
#define NTOK   197
#define DLOC   512
#define DGLB   768
#define MFINE  (B_SZ*NTOK)    // 50432 = 394*128
#define TOPK   5

// output layout (float32, concatenated):
//  gfeat            [256*768]          @ 0
//  logit_scale_exp  [1]                @ 196608
//  image_fine_list  [50432*512]        @ 196609
//  top_image_fine   [256*7*512]        @ 26017793
#define OUT_GFEAT 0
#define OUT_LSE   196608
#define OUT_FINE  196609
#define OUT_TOP   26017793

typedef ushort us8  __attribute__((ext_vector_type(8)));
typedef short  s16x8 __attribute__((ext_vector_type(8)));
typedef float  f32x4 __attribute__((ext_vector_type(4)));

__device__ inline ushort f2bf(float x){
  unsigned u = __float_as_uint(x);
  unsigned r = u + 0x7fffu + ((u>>16)&1u);   // RNE
  return (ushort)(r>>16);
}
__device__ inline float bf2f(ushort h){ return __uint_as_float(((unsigned)h)<<16); }

// ---------------- f32 -> bf16 convert ----------------
__global__ void k_f32_to_bf16(const float* __restrict__ in, ushort* __restrict__ out, int n4){
  int i = blockIdx.x*blockDim.x + threadIdx.x;
  int st = gridDim.x*blockDim.x;
  for (; i<n4; i+=st){
    float4 v = ((const float4* __restrict__)in)[i];
    ushort4 o; o.x=f2bf(v.x); o.y=f2bf(v.y); o.z=f2bf(v.z); o.w=f2bf(v.w);
    ((ushort4*)out)[i] = o;
  }
}

// ---------------- bf16 GEMM:  D[M,N] = A[M,K] @ W[N,K]^T + bias ----------------
// EPI==0: write bf16 H, atomically accumulate per-channel sum/sumsq into stats[0..N-1]/[N..2N-1]
// EPI==1: write f32 D
#define BM 128
#define BN 128
#define BK 64

template<int EPI>
__global__ __launch_bounds__(256)
void k_gemm_bt(const ushort* __restrict__ A, const ushort* __restrict__ W,
               const float* __restrict__ bias,
               ushort* __restrict__ Hout, float* __restrict__ Fout,
               float* __restrict__ stats, int M, int N, int K, int ntn){
  __shared__ ushort As[BM][BK+8];
  __shared__ ushort Ws[BN][BK+8];
  const int tid = threadIdx.x;
  const int bid = blockIdx.x;
  const int mt = bid / ntn, nt = bid % ntn;
  const int mBase = mt*BM, nBase = nt*BN;
  const int lane = tid & 63, wid = tid >> 6;
  const int wr = (wid>>1)*64, wc = (wid&1)*64;   // wave 2x2 -> 64x64 each
  const int l15 = lane & 15, lg = lane >> 4;

  f32x4 zero = {0.f,0.f,0.f,0.f};
  f32x4 acc[4][4];
  #pragma unroll
  for (int i=0;i<4;i++)
    #pragma unroll
    for (int j=0;j<4;j++) acc[i][j] = zero;

  for (int kt=0; kt<K; kt+=BK){
    __syncthreads();
    #pragma unroll
    for (int p=0;p<4;p++){
      int c = p*256 + tid;          // 1024 chunks of 16B per tile
      int row = c>>3, ko = (c&7)*8;
      us8 va = *(const us8*)&A[(size_t)(mBase+row)*K + kt + ko];
      us8 vw = *(const us8*)&W[(size_t)(nBase+row)*K + kt + ko];
      *(us8*)&As[row][ko] = va;
      *(us8*)&Ws[row][ko] = vw;
    }
    __syncthreads();
    #pragma unroll
    for (int kk=0; kk<2; kk++){
      s16x8 a[4], b[4];
      #pragma unroll
      for (int i=0;i<4;i++) a[i] = *(const s16x8*)&As[wr + i*16 + l15][kk*32 + lg*8];
      #pragma unroll
      for (int i=0;i<4;i++) b[i] = *(const s16x8*)&Ws[wc + i*16 + l15][kk*32 + lg*8];
      #pragma unroll
      for (int i=0;i<4;i++)
        #pragma unroll
        for (int j=0;j<4;j++)
          acc[i][j] = __builtin_amdgcn_mfma_f32_16x16x32_bf16(a[i], b[j], acc[i][j], 0,0,0);
    }
  }

  const int rowBase = mBase + wr;
  const int colBase = nBase + wc;
  #pragma unroll
  for (int nj=0; nj<4; nj++){
    int col = colBase + nj*16 + l15;
    float bb = bias[col];
    float s1 = 0.f, s2 = 0.f;
    #pragma unroll
    for (int mi=0; mi<4; mi++){
      #pragma unroll
      for (int j=0;j<4;j++){
        float v = acc[mi][nj][j] + bb;
        int row = rowBase + mi*16 + lg*4 + j;   // C/D: col=lane&15, row=(lane>>4)*4+reg
        if (EPI==0) Hout[(size_t)row*N + col] = f2bf(v);
        else        Fout[(size_t)row*N + col] = v;
        s1 += v; s2 += v*v;
      }
    }
    if (EPI==0){
      s1 += __shfl_xor(s1, 16); s1 += __shfl_xor(s1, 32);
      s2 += __shfl_xor(s2, 16); s2 += __shfl_xor(s2, 32);
      if (lg==0){
        atomicAdd(&stats[col],   s1);
        atomicAdd(&stats[N+col], s2);
      }
    }
  }
}

// ---------------- BN finalize: scale/shift per channel ----------------
__global__ void k_bn_finalize(const float* __restrict__ stats, const float* __restrict__ g,
                              const float* __restrict__ be, float* __restrict__ params,
                              int C, float invM){
  int c = blockIdx.x*blockDim.x + threadIdx.x;
  if (c>=C) return;
  float mean = stats[c]*invM;
  float var  = stats[C+c]*invM - mean*mean;   // biased variance
  float sc = g[c]*rsqrtf(var + 1e-5f);
  params[c]   = sc;
  params[C+c] = be[c] - mean*sc;
}

// ---------------- BN+ReLU elementwise (bf16 in/out) ----------------
__global__ void k_bn_relu(const ushort* __restrict__ h, const float* __restrict__ params,
                          ushort* __restrict__ hn, int n8, int C){
  int i = blockIdx.x*blockDim.x + threadIdx.x;
  int st = gridDim.x*blockDim.x;
  for (; i<n8; i+=st){
    us8 v = ((const us8*)h)[i];
    int c0 = (i*8) % C;
    us8 o;
    #pragma unroll
    for (int j=0;j<8;j++){
      float sc = params[c0+j];
      float sh = params[C+c0+j];
      float x = bf2f(v[j])*sc + sh;
      o[j] = f2bf(fmaxf(x, 0.f));
    }
    ((us8*)hn)[i] = o;
  }
}

// ---------------- row L2 normalize (global feature) ----------------
__global__ __launch_bounds__(256)
void k_l2norm(const float* __restrict__ gbuf, float* __restrict__ outg){
  int b = blockIdx.x, t = threadIdx.x;
  float v0 = gbuf[(size_t)b*DGLB + t];
  float v1 = gbuf[(size_t)b*DGLB + 256 + t];
  float v2 = gbuf[(size_t)b*DGLB + 512 + t];
  float s = v0*v0 + v1*v1 + v2*v2;
  s += __shfl_xor(s, 1);  s += __shfl_xor(s, 2);  s += __shfl_xor(s, 4);
  s += __shfl_xor(s, 8);  s += __shfl_xor(s, 16); s += __shfl_xor(s, 32);
  __shared__ float red[4];
  if ((t&63)==0) red[t>>6] = s;
  __syncthreads();
  float r = rsqrtf(red[0]+red[1]+red[2]+red[3]);
  outg[(size_t)b*DGLB + t]       = v0*r;
  outg[(size_t)b*DGLB + 256 + t] = v1*r;
  outg[(size_t)b*DGLB + 512 + t] = v2*r;
}

__global__ void k_scalar_exp(const float* __restrict__ ls, float* __restrict__ o){
  if (blockIdx.x==0 && threadIdx.x==0) o[0] = expf(ls[0]);
}

// ---------------- token average -> top row 6 ----------------
__global__ __launch_bounds__(128)
void k_avg(const float* __restrict__ X, float* __restrict__ T){
  int b = blockIdx.x, q = blockIdx.y;
  int c = q*128 + threadIdx.x;
  const float* p = X + (size_t)b*NTOK*DLOC + c;
  float s = 0.f;
  for (int n=0;n<NTOK;n++) s += p[(size_t)n*DLOC];
  T[((size_t)b*7 + 6)*DLOC + c] = s * (1.0f/197.0f);
}

// ---------------- top-k indices (descending, ties -> lower index) ----------------
__global__ void k_topk(const float* __restrict__ attn, int* __restrict__ idx){
  int b = blockIdx.x*blockDim.x + threadIdx.x;
  if (b >= B_SZ) return;
  const float* a = attn + (size_t)b*(NTOK-1);
  int ch[TOPK];
  #pragma unroll
  for (int j=0;j<TOPK;j++){
    float best = -3.4e38f; int bi = 0;
    for (int i=0;i<NTOK-1;i++){
      bool used = false;
      #pragma unroll
      for (int q=0;q<TOPK;q++) used |= (q<j && ch[q]==i);
      float v = a[i];
      if (!used && v>best){ best=v; bi=i; }
    }
    ch[j]=bi;
  }
  idx[b*8+0] = 0;
  #pragma unroll
  for (int j=0;j<TOPK;j++) idx[b*8+1+j] = ch[j]+1;
}

// ---------------- gather top rows ----------------
__global__ __launch_bounds__(128)
void k_gather(const float* __restrict__ X, const int* __restrict__ idx, float* __restrict__ T){
  int g = blockIdx.x;           // 0..B*6-1
  int b = g/6, j = g%6;
  int src = idx[b*8+j];
  const float* s = X + ((size_t)b*NTOK + src)*DLOC;
  float* d = T + ((size_t)b*7 + j)*DLOC;
  for (int t=threadIdx.x; t<DLOC; t+=128) d[t] = s[t];
}

// ---------------- launch ----------------
extern "C" void kernel_launch(void* const* d_in, const int* in_sizes, int n_in,
                              void* d_out, int out_size, void* d_ws, size_t ws_size,
                              hipStream_t stream){
  const float* image_features = (const float*)d_in[0];
  const float* fine_feat      = (const float*)d_in[1];
  const float* fine_attn      = (const float*)d_in[2];
  const float* logit_scale    = (const float*)d_in[3];
  const float* vpt_w1  = (const float*)d_in[4];
  const float* vpt_b1  = (const float*)d_in[5];
  const float* vpt_g1  = (const float*)d_in[6];
  const float* vpt_be1 = (const float*)d_in[7];
  const float* vpt_w2  = (const float*)d_in[8];
  const float* vpt_b2  = (const float*)d_in[9];
  const float* mid_w1  = (const float*)d_in[10];
  const float* mid_b1  = (const float*)d_in[11];
  const float* mid_g1  = (const float*)d_in[12];
  const float* mid_be1 = (const float*)d_in[13];
  const float* mid_w2  = (const float*)d_in[14];
  const float* mid_b2  = (const float*)d_in[15];

  float* out = (float*)d_out;
  char* ws = (char*)d_ws;
  size_t off = 0;
  auto alloc = [&](size_t bytes)->void*{
    void* p = ws + off; off += (bytes + 255) & ~(size_t)255; return p;
  };
  ushort* x_bf  = (ushort*)alloc((size_t)MFINE*DLOC*2);   // fine input bf16, later reused for hn
  ushort* h_bf  = (ushort*)alloc((size_t)MFINE*DLOC*2);   // GEMM1 output
  ushort* wm1   = (ushort*)alloc(512*512*2);
  ushort* wm2   = (ushort*)alloc(512*512*2);
  ushort* wv1   = (ushort*)alloc(768*512*2);
  ushort* wv2   = (ushort*)alloc((size_t)768*768*2);
  ushort* img_bf= (ushort*)alloc(256*512*2);
  ushort* h1g   = (ushort*)alloc(256*768*2);
  ushort* hn1g  = (ushort*)alloc(256*768*2);
  float*  gbuf  = (float*)alloc(256*768*4);
  float*  stats_f = (float*)alloc(512*2*4);
  float*  stats_g = (float*)alloc(768*2*4);
  float*  par_f   = (float*)alloc(512*2*4);
  float*  par_g   = (float*)alloc(768*2*4);
  int*    idx     = (int*)alloc(256*8*4);

  hipMemsetAsync(stats_f, 0, 512*2*4, stream);
  hipMemsetAsync(stats_g, 0, 768*2*4, stream);

  // converts
  k_f32_to_bf16<<<2048,256,0,stream>>>(fine_feat, x_bf, MFINE*DLOC/4);
  k_f32_to_bf16<<<64,  256,0,stream>>>(image_features, img_bf, 256*512/4);
  k_f32_to_bf16<<<64,  256,0,stream>>>(mid_w1, wm1, 512*512/4);
  k_f32_to_bf16<<<64,  256,0,stream>>>(mid_w2, wm2, 512*512/4);
  k_f32_to_bf16<<<96,  256,0,stream>>>(vpt_w1, wv1, 768*512/4);
  k_f32_to_bf16<<<144, 256,0,stream>>>(vpt_w2, wv2, 768*768/4);

  // GEMM1 (h = x @ w1^T + b1) + channel stats
  k_gemm_bt<0><<<(MFINE/BM)*(DLOC/BN),256,0,stream>>>(x_bf, wm1, mid_b1, h_bf, nullptr, stats_f, MFINE, DLOC, DLOC, DLOC/BN);
  k_gemm_bt<0><<<(B_SZ/BM)*(DGLB/BN),256,0,stream>>>(img_bf, wv1, vpt_b1, h1g, nullptr, stats_g, B_SZ, DGLB, DLOC, DGLB/BN);

  // BN finalize
  k_bn_finalize<<<2,256,0,stream>>>(stats_f, mid_g1, mid_be1, par_f, 512, 1.0f/(float)MFINE);
  k_bn_finalize<<<3,256,0,stream>>>(stats_g, vpt_g1, vpt_be1, par_g, 768, 1.0f/(float)B_SZ);

  // BN + ReLU
  k_bn_relu<<<2048,256,0,stream>>>(h_bf, par_f, x_bf, MFINE*DLOC/8, 512);
  k_bn_relu<<<96,  256,0,stream>>>(h1g, par_g, hn1g, B_SZ*DGLB/8, 768);

  // GEMM2
  float* Xout = out + OUT_FINE;
  k_gemm_bt<1><<<(MFINE/BM)*(DLOC/BN),256,0,stream>>>(x_bf, wm2, mid_b2, nullptr, Xout, nullptr, MFINE, DLOC, DLOC, DLOC/BN);
  k_gemm_bt<1><<<(B_SZ/BM)*(DGLB/BN),256,0,stream>>>(hn1g, wv2, vpt_b2, nullptr, gbuf, nullptr, B_SZ, DGLB, DGLB, DGLB/BN);

  // epilogue kernels
  k_l2norm<<<B_SZ,256,0,stream>>>(gbuf, out + OUT_GFEAT);
  k_scalar_exp<<<1,64,0,stream>>>(logit_scale, out + OUT_LSE);

  float* Tout = out + OUT_TOP;
  dim3 ag(B_SZ,4);
  k_avg<<<ag,128,0,stream>>>(Xout, Tout);
  k_topk<<<4,64,0,stream>>>(fine_attn, idx);
  k_gather<<<B_SZ*6,128,0,stream>>>(Xout, idx, Tout);
}